// Round 6
// baseline (240.940 us; speedup 1.0000x reference)
//
#include <hip/hip_runtime.h>
#include <hip/hip_bf16.h>
#include <math.h>

// Loss_26886495273741: uniformity loss
//   dots = F F^T (diag masked), I = argmax_row(dots), d = ||F - F[I] + eps||_2
//   loss = -mean(log(n*d))
// F: [16384, 256] fp32.
//
// Round 6: SYMMETRIC MFMA kernel — each upper-triangle tile (rs,t) updates
//   both stripe rs's row-argmax (A-side, in-register fold + one u64 atomic
//   per row per block) and stripe t's row-argmax (B-side: per-column max
//   over the tile's rows -> u64 panel written to scratch[t][rs][col]).
//   Halves MFMA work and B-streaming vs round 4, keeping the verified
//   round-4 inner loop (2-slot dbuf, plain __syncthreads, no sched games).
//   dist_loss merges packed[r] with scratch[tR][0..tR][r&127] per row.

#define NROWS 16384
#define DIM   256
#define BM    128
#define BN    128
#define EPSF  1e-6f

typedef __attribute__((ext_vector_type(8))) __bf16 bf16x8;
typedef __attribute__((ext_vector_type(4))) float f32x4;

typedef const __attribute__((address_space(1))) void* gas1_t;
typedef __attribute__((address_space(3))) void* las3_t;

__device__ __forceinline__ void glds16(const void* g, void* l) {
    __builtin_amdgcn_global_load_lds((gas1_t)g, (las3_t)l, 16, 0, 0);
}

__device__ __forceinline__ unsigned short f2bf(float f) {
    union { float f; unsigned u; } x; x.f = f;
    const unsigned u = x.u;
    return (unsigned short)((u + 0x7FFFu + ((u >> 16) & 1u)) >> 16);  // RNE
}

__device__ __forceinline__ unsigned umax2(unsigned a, unsigned b) {
    return a > b ? a : b;
}

// ---------------- K0: convert fp32 -> bf16, zero packed ----------------
__global__ __launch_bounds__(256)
void convert_kernel(const float* __restrict__ F, unsigned short* __restrict__ Fb,
                    unsigned long long* __restrict__ packed)
{
    const int t = blockIdx.x * 256 + threadIdx.x;     // 524288 threads
    const float4 a = *reinterpret_cast<const float4*>(F + (size_t)t * 8);
    const float4 b = *reinterpret_cast<const float4*>(F + (size_t)t * 8 + 4);
    ushort4 lo, hi;
    lo.x = f2bf(a.x); lo.y = f2bf(a.y); lo.z = f2bf(a.z); lo.w = f2bf(a.w);
    hi.x = f2bf(b.x); hi.y = f2bf(b.y); hi.z = f2bf(b.z); hi.w = f2bf(b.w);
    *reinterpret_cast<ushort4*>(Fb + (size_t)t * 8)     = lo;
    *reinterpret_cast<ushort4*>(Fb + (size_t)t * 8 + 4) = hi;
    if (t < NROWS) packed[t] = 0ull;
}

// ---------------- K1: symmetric bf16 MFMA + two-sided argmax ----------------
__global__ __launch_bounds__(256, 2)
void mfma_sym_kernel(const unsigned short* __restrict__ Fb,
                     unsigned long long* __restrict__ packed,
                     unsigned long long* __restrict__ scratch)
{
    __shared__ __align__(16) unsigned short As[BM * DIM];   // 64 KB
    unsigned short* const Bs = As;              // 2 x 8192-short B dbuf
    unsigned* const cmb = (unsigned*)&As[16384];            // [2][128] u32

    const int tid  = threadIdx.x;
    const int w    = tid >> 6;
    const int l    = tid & 63;
    const int rs   = (int)blockIdx.x >> 3;      // row stripe 0..127
    const int ck   = (int)blockIdx.x & 7;       // chunk-of-stripe 0..7
    const int span = 128 - rs;
    const int t0   = rs + (span * ck) / 8;
    const int t1   = rs + (span * (ck + 1)) / 8;
    if (t0 >= t1) return;                       // block-uniform

    const int row0 = rs * BM;
    const int wr   = w >> 1;
    const int wrow = wr * 64;
    const int wcol = (w & 1) * 64;
    const int lc   = l & 15;
    const int lr4  = l >> 4;

    // ---- stage A panel: LDS phys (row, cp) holds global chunk cp^(row&7) ----
    {
        const int lr = l >> 5;                       // 0..1
        const int sc = (l & 31) ^ (2 * w + lr);      // pre-permuted source chunk
        #pragma unroll
        for (int q = 0; q < 16; ++q)
            glds16(Fb + (size_t)(row0 + 8 * q + 2 * w + lr) * DIM + sc * 8,
                   &As[(q * 4 + w) * 512]);
    }
    __syncthreads();

    // ---- extract A fragments to registers: af[i][kt] ----
    bf16x8 af[4][8];
    #pragma unroll
    for (int i = 0; i < 4; ++i) {
        const int r = wrow + i * 16 + lc;
        #pragma unroll
        for (int kt = 0; kt < 8; ++kt) {
            const int g = kt * 4 + lr4;
            af[i][kt] = *reinterpret_cast<const bf16x8*>(
                &As[r * 256 + ((g ^ (r & 7)) << 3)]);
        }
    }
    __syncthreads();   // A region reusable as B dbuf

    // ---- B staging geometry (slice = 128 cols x 64 K-shorts, 8-way swizzle) ----
    const int bsc = (l & 7) ^ ((l >> 3) & 7);   // pre-permuted source chunk
    const int bco = l >> 3;                     // col within 8-col group

    // stage first slice (t0, kq=0) into slot 0
    #pragma unroll
    for (int q = 0; q < 4; ++q) {
        const int grp = q * 4 + w;
        glds16(Fb + (size_t)(t0 * BM + grp * 8 + bco) * DIM + bsc * 8,
               &Bs[grp * 512]);
    }

    f32x4 acc[4][4];
    #pragma unroll
    for (int i = 0; i < 4; ++i)
        #pragma unroll
        for (int j = 0; j < 4; ++j)
            acc[i][j] = (f32x4){512.f, 512.f, 512.f, 512.f};   // monotonic bias

    unsigned best[4][4] = {};   // (biased bits & ~0x7FF) | (2047 - block-local col)

    for (int t = t0; t < t1; ++t) {
        const bool dt = (t == rs);              // diagonal tile
        #pragma unroll
        for (int kq = 0; kq < 4; ++kq) {
            __syncthreads();   // slice (t,kq) staged; prior reads of other buf done

            // prefetch next slice into the other slot
            const int nt  = (kq < 3) ? t : t + 1;
            const int nkq = (kq < 3) ? kq + 1 : 0;
            if (nt < t1) {
                #pragma unroll
                for (int q = 0; q < 4; ++q) {
                    const int grp = q * 4 + w;
                    glds16(Fb + (size_t)(nt * BM + grp * 8 + bco) * DIM
                               + nkq * 64 + bsc * 8,
                           &Bs[((kq & 1) ^ 1) * 8192 + grp * 512]);
                }
            }

            const int rbase = (kq & 1) * 8192;
            #pragma unroll
            for (int h = 0; h < 2; ++h) {           // two K=32 halves
                bf16x8 bfv[4];
                #pragma unroll
                for (int j = 0; j < 4; ++j) {
                    const int c = wcol + j * 16 + lc;
                    const int p = (h * 4 + lr4) ^ (c & 7);
                    bfv[j] = *reinterpret_cast<const bf16x8*>(
                        &Bs[rbase + c * 64 + p * 8]);
                }
                #pragma unroll
                for (int j = 0; j < 4; ++j)
                    #pragma unroll
                    for (int i = 0; i < 4; ++i)
                        acc[i][j] = __builtin_amdgcn_mfma_f32_16x16x32_bf16(
                            af[i][kq * 2 + h], bfv[j], acc[i][j], 0, 0, 0);
            }
        }

        // ---- B-side fold: per-column max over this tile's 128 rows ----
        #pragma unroll
        for (int j = 0; j < 4; ++j) {
            unsigned kb = 0u;
            #pragma unroll
            for (int i = 0; i < 4; ++i)
                #pragma unroll
                for (int g = 0; g < 4; ++g) {
                    const int r_loc = wrow + i * 16 + lr4 * 4 + g;
                    unsigned key = (__float_as_uint(acc[i][j][g]) & 0xFFFFF800u)
                                   | (unsigned)(127 - r_loc);
                    if (dt && (wcol + j * 16 + lc == r_loc)) key = 0u;
                    kb = umax2(kb, key);
                }
            kb = umax2(kb, (unsigned)__shfl_xor((int)kb, 16));
            kb = umax2(kb, (unsigned)__shfl_xor((int)kb, 32));
            if (lr4 == 0) cmb[wr * 128 + wcol + j * 16 + lc] = kb;
        }

        // ---- A-side fold into running per-row argmax (u32 keys) ----
        const int tl = t - t0;                   // block-local tile 0..15
        unsigned cb[4];
        #pragma unroll
        for (int j = 0; j < 4; ++j)
            cb[j] = 2047u - (unsigned)(tl * 128 + wcol + j * 16 + lc);

        if (dt) {
            #pragma unroll
            for (int i = 0; i < 4; ++i)
                #pragma unroll
                for (int g = 0; g < 4; ++g) {
                    const int r_loc = wrow + i * 16 + lr4 * 4 + g;
                    unsigned bk = best[i][g];
                    #pragma unroll
                    for (int j = 0; j < 4; ++j) {
                        unsigned key = (__float_as_uint(acc[i][j][g])
                                        & 0xFFFFF800u) | cb[j];
                        if (wcol + j * 16 + lc == r_loc) key = 0u;
                        bk = umax2(bk, key);
                        acc[i][j][g] = 512.f;
                    }
                    best[i][g] = bk;
                }
        } else {
            #pragma unroll
            for (int i = 0; i < 4; ++i)
                #pragma unroll
                for (int g = 0; g < 4; ++g) {
                    const unsigned k0 = (__float_as_uint(acc[i][0][g]) & 0xFFFFF800u) | cb[0];
                    const unsigned k1 = (__float_as_uint(acc[i][1][g]) & 0xFFFFF800u) | cb[1];
                    const unsigned k2 = (__float_as_uint(acc[i][2][g]) & 0xFFFFF800u) | cb[2];
                    const unsigned k3 = (__float_as_uint(acc[i][3][g]) & 0xFFFFF800u) | cb[3];
                    best[i][g] = umax2(best[i][g],
                                       umax2(umax2(k0, k1), umax2(k2, k3)));
                    acc[i][0][g] = 512.f; acc[i][1][g] = 512.f;
                    acc[i][2][g] = 512.f; acc[i][3][g] = 512.f;
                }
        }

        // ---- combine the two row-halves, write B-side panel to scratch ----
        __syncthreads();   // cmb visible
        if (w < 2) {
            const int c = w * 64 + l;           // 0..127
            const unsigned km = umax2(cmb[c], cmb[128 + c]);
            const unsigned grow = (unsigned)row0 + (127u - (km & 0x7FFu));
            const unsigned long long pk =
                ((unsigned long long)(km & 0xFFFFF800u) << 32) |
                (0xFFFFFFFFu - grow);
            scratch[((size_t)t * 128 + rs) * 128 + c] = pk;
        }
        // next tile's cmb write is separated by >=4 __syncthreads -> safe
    }

    // ---- A-side: reduce over 16-lane col group, one u64 atomic per row ----
    #pragma unroll
    for (int i = 0; i < 4; ++i)
        #pragma unroll
        for (int g = 0; g < 4; ++g) {
            unsigned key = best[i][g];
            #pragma unroll
            for (int m = 8; m >= 1; m >>= 1)
                key = umax2(key, (unsigned)__shfl_xor((int)key, m));
            if (lc == 0) {
                const int r = row0 + wrow + i * 16 + lr4 * 4 + g;
                const unsigned c = (unsigned)(t0 * BM) + (2047u - (key & 0x7FFu));
                const unsigned long long pk =
                    ((unsigned long long)(key & 0xFFFFF800u) << 32) |
                    (0xFFFFFFFFu - c);
                atomicMax(&packed[r], pk);
            }
        }
}

// ------- K2: merge two-sided candidates + exact fp32 distances + log -------
__global__ __launch_bounds__(256)
void dist_loss_kernel(const float* __restrict__ F,
                      const unsigned long long* __restrict__ packed,
                      const unsigned long long* __restrict__ scratch,
                      double* __restrict__ partials)
{
    const int tid  = threadIdx.x;
    const int lane = tid & 63;
    const int w    = tid >> 6;
    const int gw   = blockIdx.x * 4 + w;       // 1024 waves
    double local = 0.0;
    for (int r = gw; r < NROWS; r += 1024) {
        const int tR = r >> 7;
        const int cl = r & 127;
        unsigned long long best = packed[r];
        const unsigned long long* base = scratch + (size_t)tR * 16384 + cl;
        if (lane <= tR) {
            unsigned long long v = base[(size_t)lane * 128];
            if (lane + 64 <= tR) {
                const unsigned long long v2 = base[(size_t)(lane + 64) * 128];
                if (v2 > v) v = v2;
            }
            if (v > best) best = v;
        }
        #pragma unroll
        for (int m = 32; m >= 1; m >>= 1) {
            const unsigned long long o = __shfl_xor(best, m);
            if (o > best) best = o;
        }
        const int idx = (int)(0xFFFFFFFFu - (unsigned)(best & 0xFFFFFFFFull));

        const float4 a = *reinterpret_cast<const float4*>(
            F + (size_t)r * DIM + (lane << 2));
        const float4 b = *reinterpret_cast<const float4*>(
            F + (size_t)idx * DIM + (lane << 2));
        const float dx = a.x - b.x + EPSF;
        const float dy = a.y - b.y + EPSF;
        const float dz = a.z - b.z + EPSF;
        const float dw = a.w - b.w + EPSF;
        float ss = dx * dx + dy * dy + dz * dz + dw * dw;
        #pragma unroll
        for (int m = 32; m >= 1; m >>= 1) ss += __shfl_xor(ss, m);
        if (lane == 0)
            local += 0.5 * log((double)ss) + log((double)NROWS);
    }
    __shared__ double sm[4];
    if (lane == 0) sm[w] = local;
    __syncthreads();
    if (tid == 0) partials[blockIdx.x] = sm[0] + sm[1] + sm[2] + sm[3];
}

__global__ __launch_bounds__(256)
void finalize_kernel(const double* __restrict__ partials, float* __restrict__ out)
{
    const int tid = threadIdx.x;
    double v = partials[tid];
    #pragma unroll
    for (int m = 32; m >= 1; m >>= 1) v += __shfl_xor(v, m);
    __shared__ double sm[4];
    if ((tid & 63) == 0) sm[tid >> 6] = v;
    __syncthreads();
    if (tid == 0) out[0] = (float)(-(sm[0] + sm[1] + sm[2] + sm[3]) / (double)NROWS);
}

extern "C" void kernel_launch(void* const* d_in, const int* in_sizes, int n_in,
                              void* d_out, int out_size, void* d_ws, size_t ws_size,
                              hipStream_t stream)
{
    const float* F   = (const float*)d_in[0];
    float*       out = (float*)d_out;

    char* ws = (char*)d_ws;
    unsigned short*     Fb       = (unsigned short*)ws;                  // 8 MB
    unsigned long long* packed   = (unsigned long long*)(ws + 8388608);  // 128 KB
    unsigned long long* scratch  = (unsigned long long*)(ws + 8519680);  // 16 MB
    double*             partials = (double*)(ws + 25296896);             // 2 KB

    convert_kernel<<<2048, 256, 0, stream>>>(F, Fb, packed);
    mfma_sym_kernel<<<(NROWS / BM) * 8, 256, 0, stream>>>(Fb, packed, scratch);
    dist_loss_kernel<<<256, 256, 0, stream>>>(F, packed, scratch, partials);
    finalize_kernel<<<1, 256, 0, stream>>>(partials, out);
}

// Round 7
// 126.488 us; speedup vs baseline: 1.9049x; 1.9049x over previous
//
#include <hip/hip_runtime.h>
#include <hip/hip_bf16.h>
#include <math.h>

// Loss_26886495273741: uniformity loss
//   dots = F F^T (diag masked), I = argmax_row(dots), d = ||F - F[I] + eps||_2
//   loss = -mean(log(n*d))
// F: [16384, 256] fp32.
//
// Round 7: symmetric MFMA, LOW-PRESSURE chassis (no af-persist -> no spills).
//   Grid = 128 stripes x 8 chunk-blocks over the upper triangle.
//   A panel [128][256] bf16 resident in LDS (64 KB, XOR chunk-swizzle);
//   B slice [128 cols][32 K] double-buffered (2 x 8 KB); 1 barrier/step.
//   LDS = exactly 80 KB -> 2 blocks/CU. A-frags re-read from LDS per step
//   (R3-proven, VGPR ~100, no spill traffic).
//   A-side: in-register per-row argmax, one u64 atomicMax(packed) per row.
//   B-side: per-column fold + lr4-butterfly, u64 atomicMax into scratch
//   [t][rs][col] (zeroed in K0; 2 atomics/address, order-independent).
//   K2 merges packed[r] with scratch[tR][0..tR][r&127], exact fp32 distance.

#define NROWS 16384
#define DIM   256
#define BM    128
#define BN    128
#define EPSF  1e-6f

typedef __attribute__((ext_vector_type(8))) __bf16 bf16x8;
typedef __attribute__((ext_vector_type(4))) float f32x4;

typedef const __attribute__((address_space(1))) void* gas1_t;
typedef __attribute__((address_space(3))) void* las3_t;

__device__ __forceinline__ void glds16(const void* g, void* l) {
    __builtin_amdgcn_global_load_lds((gas1_t)g, (las3_t)l, 16, 0, 0);
}

__device__ __forceinline__ unsigned short f2bf(float f) {
    union { float f; unsigned u; } x; x.f = f;
    const unsigned u = x.u;
    return (unsigned short)((u + 0x7FFFu + ((u >> 16) & 1u)) >> 16);  // RNE
}

__device__ __forceinline__ unsigned umax2(unsigned a, unsigned b) {
    return a > b ? a : b;
}

// -------- K0: convert fp32 -> bf16, zero packed + scratch --------
__global__ __launch_bounds__(256)
void convert_kernel(const float* __restrict__ F, unsigned short* __restrict__ Fb,
                    unsigned long long* __restrict__ packed,
                    unsigned long long* __restrict__ scratch)
{
    const int t = blockIdx.x * 256 + threadIdx.x;     // 524288 threads
    const float4 a = *reinterpret_cast<const float4*>(F + (size_t)t * 8);
    const float4 b = *reinterpret_cast<const float4*>(F + (size_t)t * 8 + 4);
    ushort4 lo, hi;
    lo.x = f2bf(a.x); lo.y = f2bf(a.y); lo.z = f2bf(a.z); lo.w = f2bf(a.w);
    hi.x = f2bf(b.x); hi.y = f2bf(b.y); hi.z = f2bf(b.z); hi.w = f2bf(b.w);
    *reinterpret_cast<ushort4*>(Fb + (size_t)t * 8)     = lo;
    *reinterpret_cast<ushort4*>(Fb + (size_t)t * 8 + 4) = hi;
    if (t < NROWS) packed[t] = 0ull;
    #pragma unroll
    for (int q = 0; q < 4; ++q)                       // 2M u64 = 16 MB
        scratch[(size_t)t * 4 + q] = 0ull;
}

// -------- K1: symmetric bf16 MFMA + two-sided argmax --------
__global__ __launch_bounds__(256, 2)
void mfma_sym_kernel(const unsigned short* __restrict__ Fb,
                     unsigned long long* __restrict__ packed,
                     unsigned long long* __restrict__ scratch)
{
    __shared__ __align__(16) unsigned short As[BM * DIM];   // 64 KB, persistent
    __shared__ __align__(16) unsigned short Bs[2 * 4096];   // 16 KB dbuf

    const int tid  = threadIdx.x;
    const int w    = tid >> 6;
    const int l    = tid & 63;
    const int rs   = (int)blockIdx.x >> 3;      // row stripe 0..127
    const int ck   = (int)blockIdx.x & 7;       // chunk-of-stripe 0..7
    const int span = 128 - rs;
    const int t0   = rs + (span * ck) / 8;
    const int t1   = rs + (span * (ck + 1)) / 8;
    if (t0 >= t1) return;                       // block-uniform

    const int row0 = rs * BM;
    const int wrow = (w >> 1) * 64;
    const int wcol = (w & 1) * 64;
    const int lc   = l & 15;
    const int lr4  = l >> 4;

    // ---- stage A panel: LDS phys (row, cp) holds global chunk cp^(row&7) ----
    {
        const int lr = l >> 5;                       // 0..1
        const int sc = (l & 31) ^ (2 * w + lr);      // pre-permuted source chunk
        #pragma unroll
        for (int q = 0; q < 16; ++q)
            glds16(Fb + (size_t)(row0 + 8 * q + 2 * w + lr) * DIM + sc * 8,
                   &As[(q * 4 + w) * 512]);
    }

    // ---- B staging geometry: slice [128 cols][4 chunks of 8 shorts] ----
    // phys chunk p holds logical p ^ ((col>>1)&3)  (2-way bank aliasing = free)
    const int bsc = (l & 3) ^ ((l >> 3) & 3);   // pre-permuted source chunk
    const int bco = l >> 2;                     // col within wave's 16-col group

    // stage first slice (t0, k0=0) into slot 0
    #pragma unroll
    for (int q = 0; q < 2; ++q)
        glds16(Fb + (size_t)(t0 * BM + q * 64 + w * 16 + bco) * DIM + bsc * 8,
               &Bs[q * 2048 + w * 512]);

    f32x4 acc[4][4];
    #pragma unroll
    for (int i = 0; i < 4; ++i)
        #pragma unroll
        for (int j = 0; j < 4; ++j)
            acc[i][j] = (f32x4){512.f, 512.f, 512.f, 512.f};   // monotonic bias

    unsigned best[4][4] = {};   // (biased bits & ~0x7FF) | (2047 - block-local col)

    for (int t = t0; t < t1; ++t) {
        const bool dt = (t == rs);              // diagonal tile
        #pragma unroll
        for (int kq = 0; kq < 8; ++kq) {        // K=32 steps
            __syncthreads();   // slice (t,kq) staged; prior reads of other slot done

            // prefetch next slice into the other slot
            const int nt = (kq < 7) ? t : t + 1;
            const int nk = (kq < 7) ? (kq + 1) * 32 : 0;
            if (nt < t1) {
                #pragma unroll
                for (int q = 0; q < 2; ++q)
                    glds16(Fb + (size_t)(nt * BM + q * 64 + w * 16 + bco) * DIM
                               + nk + bsc * 8,
                           &Bs[((kq & 1) ^ 1) * 4096 + q * 2048 + w * 512]);
            }

            const int rbase = (kq & 1) * 4096;
            bf16x8 afv[4], bfv[4];
            #pragma unroll
            for (int i = 0; i < 4; ++i) {
                const int r = wrow + i * 16 + lc;
                const int g = kq * 4 + lr4;
                afv[i] = *reinterpret_cast<const bf16x8*>(
                    &As[r * 256 + ((g ^ (r & 7)) << 3)]);
            }
            #pragma unroll
            for (int j = 0; j < 4; ++j) {
                const int c = wcol + j * 16 + lc;
                const int p = lr4 ^ ((c >> 1) & 3);
                bfv[j] = *reinterpret_cast<const bf16x8*>(
                    &Bs[rbase + c * 32 + p * 8]);
            }
            #pragma unroll
            for (int j = 0; j < 4; ++j)
                #pragma unroll
                for (int i = 0; i < 4; ++i)
                    acc[i][j] = __builtin_amdgcn_mfma_f32_16x16x32_bf16(
                        afv[i], bfv[j], acc[i][j], 0, 0, 0);
        }

        // ---- B-side fold: per-column max over the tile's 128 rows ----
        #pragma unroll
        for (int j = 0; j < 4; ++j) {
            unsigned kb = 0u;
            #pragma unroll
            for (int i = 0; i < 4; ++i)
                #pragma unroll
                for (int g = 0; g < 4; ++g) {
                    const int r_loc = wrow + i * 16 + lr4 * 4 + g;
                    unsigned key = (__float_as_uint(acc[i][j][g]) & 0xFFFFF800u)
                                   | (unsigned)(127 - r_loc);
                    if (dt && (wcol + j * 16 + lc == r_loc)) key = 0u;
                    kb = umax2(kb, key);
                }
            kb = umax2(kb, (unsigned)__shfl_xor((int)kb, 16));
            kb = umax2(kb, (unsigned)__shfl_xor((int)kb, 32));
            if (lr4 == 0) {    // 64-row half max -> one atomic per col per half
                const unsigned grow = (unsigned)row0 + (127u - (kb & 0x7FFu));
                const unsigned long long pk =
                    ((unsigned long long)(kb & 0xFFFFF800u) << 32) |
                    (0xFFFFFFFFu - grow);
                atomicMax(&scratch[((size_t)t * 128 + rs) * 128
                                   + wcol + j * 16 + lc], pk);
            }
        }

        // ---- A-side fold into running per-row argmax ----
        const int tl = t - t0;                   // block-local tile (<=15)
        unsigned cb[4];
        #pragma unroll
        for (int j = 0; j < 4; ++j)
            cb[j] = 2047u - (unsigned)(tl * 128 + wcol + j * 16 + lc);

        if (dt) {
            #pragma unroll
            for (int i = 0; i < 4; ++i)
                #pragma unroll
                for (int g = 0; g < 4; ++g) {
                    const int r_loc = wrow + i * 16 + lr4 * 4 + g;
                    unsigned bk = best[i][g];
                    #pragma unroll
                    for (int j = 0; j < 4; ++j) {
                        unsigned key = (__float_as_uint(acc[i][j][g])
                                        & 0xFFFFF800u) | cb[j];
                        if (wcol + j * 16 + lc == r_loc) key = 0u;
                        bk = umax2(bk, key);
                        acc[i][j][g] = 512.f;
                    }
                    best[i][g] = bk;
                }
        } else {
            #pragma unroll
            for (int i = 0; i < 4; ++i)
                #pragma unroll
                for (int g = 0; g < 4; ++g) {
                    const unsigned k0 = (__float_as_uint(acc[i][0][g]) & 0xFFFFF800u) | cb[0];
                    const unsigned k1 = (__float_as_uint(acc[i][1][g]) & 0xFFFFF800u) | cb[1];
                    const unsigned k2 = (__float_as_uint(acc[i][2][g]) & 0xFFFFF800u) | cb[2];
                    const unsigned k3 = (__float_as_uint(acc[i][3][g]) & 0xFFFFF800u) | cb[3];
                    best[i][g] = umax2(best[i][g],
                                       umax2(umax2(k0, k1), umax2(k2, k3)));
                    acc[i][0][g] = 512.f; acc[i][1][g] = 512.f;
                    acc[i][2][g] = 512.f; acc[i][3][g] = 512.f;
                }
        }
    }

    // ---- A-side: reduce over 16-lane col group, one u64 atomic per row ----
    #pragma unroll
    for (int i = 0; i < 4; ++i)
        #pragma unroll
        for (int g = 0; g < 4; ++g) {
            unsigned key = best[i][g];
            #pragma unroll
            for (int m = 8; m >= 1; m >>= 1)
                key = umax2(key, (unsigned)__shfl_xor((int)key, m));
            if (lc == 0) {
                const int r = row0 + wrow + i * 16 + lr4 * 4 + g;
                const unsigned c = (unsigned)(t0 * BM) + (2047u - (key & 0x7FFu));
                const unsigned long long pk =
                    ((unsigned long long)(key & 0xFFFFF800u) << 32) |
                    (0xFFFFFFFFu - c);
                atomicMax(&packed[r], pk);
            }
        }
}

// ------- K2: merge two-sided candidates + exact fp32 distances + log -------
__global__ __launch_bounds__(256)
void dist_loss_kernel(const float* __restrict__ F,
                      const unsigned long long* __restrict__ packed,
                      const unsigned long long* __restrict__ scratch,
                      double* __restrict__ partials)
{
    const int tid  = threadIdx.x;
    const int lane = tid & 63;
    const int w    = tid >> 6;
    const int gw   = blockIdx.x * 4 + w;       // 1024 waves
    double local = 0.0;
    for (int r = gw; r < NROWS; r += 1024) {
        const int tR = r >> 7;
        const int cl = r & 127;
        unsigned long long best = packed[r];
        const unsigned long long* base = scratch + (size_t)tR * 16384 + cl;
        if (lane <= tR) {
            unsigned long long v = base[(size_t)lane * 128];
            if (lane + 64 <= tR) {
                const unsigned long long v2 = base[(size_t)(lane + 64) * 128];
                if (v2 > v) v = v2;
            }
            if (v > best) best = v;
        }
        #pragma unroll
        for (int m = 32; m >= 1; m >>= 1) {
            const unsigned long long o = __shfl_xor(best, m);
            if (o > best) best = o;
        }
        const int idx = (int)(0xFFFFFFFFu - (unsigned)(best & 0xFFFFFFFFull));

        const float4 a = *reinterpret_cast<const float4*>(
            F + (size_t)r * DIM + (lane << 2));
        const float4 b = *reinterpret_cast<const float4*>(
            F + (size_t)idx * DIM + (lane << 2));
        const float dx = a.x - b.x + EPSF;
        const float dy = a.y - b.y + EPSF;
        const float dz = a.z - b.z + EPSF;
        const float dw = a.w - b.w + EPSF;
        float ss = dx * dx + dy * dy + dz * dz + dw * dw;
        #pragma unroll
        for (int m = 32; m >= 1; m >>= 1) ss += __shfl_xor(ss, m);
        if (lane == 0)
            local += 0.5 * log((double)ss) + log((double)NROWS);
    }
    __shared__ double sm[4];
    if (lane == 0) sm[w] = local;
    __syncthreads();
    if (tid == 0) partials[blockIdx.x] = sm[0] + sm[1] + sm[2] + sm[3];
}

__global__ __launch_bounds__(256)
void finalize_kernel(const double* __restrict__ partials, float* __restrict__ out)
{
    const int tid = threadIdx.x;
    double v = partials[tid];
    #pragma unroll
    for (int m = 32; m >= 1; m >>= 1) v += __shfl_xor(v, m);
    __shared__ double sm[4];
    if ((tid & 63) == 0) sm[tid >> 6] = v;
    __syncthreads();
    if (tid == 0) out[0] = (float)(-(sm[0] + sm[1] + sm[2] + sm[3]) / (double)NROWS);
}

extern "C" void kernel_launch(void* const* d_in, const int* in_sizes, int n_in,
                              void* d_out, int out_size, void* d_ws, size_t ws_size,
                              hipStream_t stream)
{
    const float* F   = (const float*)d_in[0];
    float*       out = (float*)d_out;

    char* ws = (char*)d_ws;
    unsigned short*     Fb       = (unsigned short*)ws;                  // 8 MB
    unsigned long long* packed   = (unsigned long long*)(ws + 8388608);  // 128 KB
    unsigned long long* scratch  = (unsigned long long*)(ws + 8519680);  // 16 MB
    double*             partials = (double*)(ws + 25296896);             // 2 KB

    convert_kernel<<<2048, 256, 0, stream>>>(F, Fb, packed, scratch);
    mfma_sym_kernel<<<(NROWS / BM) * 8, 256, 0, stream>>>(Fb, packed, scratch);
    dist_loss_kernel<<<256, 256, 0, stream>>>(F, packed, scratch, partials);
    finalize_kernel<<<1, 256, 0, stream>>>(partials, out);
}

// Round 8
// 106.744 us; speedup vs baseline: 2.2572x; 1.1850x over previous
//
#include <hip/hip_runtime.h>
#include <hip/hip_bf16.h>
#include <math.h>

// Loss_26886495273741: uniformity loss
//   dots = F F^T (diag masked), I = argmax_row(dots), d = ||F - F[I] + eps||_2
//   loss = -mean(log(n*d))
// F: [16384, 256] fp32.
//
// Round 8: fp8(e4m3) symmetric MFMA — halves the LDS-BW wall identified in R7.
//   mfma_f32_16x16x32_fp8_fp8 (bf16 rate, half the fragment bytes).
//   LDS layouts are K-major transposed: A [k16 0..15][row 0..127][16B] (32 KB),
//   B [k16 0..3][col 0..127][16B] x2 slots (16 KB) — glds16-compatible
//   (lane x 16B contiguous) and b64 fragment reads sit at the bank floor
//   (4 addrs/bank = 128 B/cyc optimum), no XOR swizzle needed.
//   48 KB LDS -> 3 blocks/CU. K=64 slices -> 4 barriers/tile (was 8).
//   Two-sided argmax (A-side in-register fold + packed u64 atomicMax;
//   B-side per-column fold -> atomicMax into scratch[t][rs][col]) as R7.
//   Distances still exact fp32 in K2.

#define NROWS 16384
#define DIM   256
#define BM    128
#define BN    128
#define EPSF  1e-6f

typedef __attribute__((ext_vector_type(4))) float f32x4;

typedef const __attribute__((address_space(1))) void* gas1_t;
typedef __attribute__((address_space(3))) void* las3_t;

__device__ __forceinline__ void glds16(const void* g, void* l) {
    __builtin_amdgcn_global_load_lds((gas1_t)g, (las3_t)l, 16, 0, 0);
}

__device__ __forceinline__ unsigned umax2(unsigned a, unsigned b) {
    return a > b ? a : b;
}

// exact RNE fp32 -> OCP e4m3fn (no overflow for |x| < 448; FTZ below 2^-9)
__device__ __forceinline__ unsigned f2e4m3(float f) {
    union { float f; unsigned u; } x; x.f = f;
    const unsigned s = (x.u >> 24) & 0x80u;
    const unsigned au = x.u & 0x7FFFFFFFu;
    float af = __uint_as_float(au);
    if (au < 0x3B800000u) {                    // |x| < 2^-8: subnormal region
        // code LSB = 2^-9; round-to-nearest (ties handled adequately)
        const int q = (int)(af * 512.0f + 0.5f);
        return s | (unsigned)q;                // q <= 2 here (fits subnormal/normal)
    }
    // normal: RNE on 3-bit mantissa
    const unsigned add = 0x7FFFFu + ((au >> 20) & 1u);
    const unsigned v = au + add;
    const unsigned e = (v >> 23) - 120u;       // e4m3 exponent (bias 7)
    return s | (e << 3) | ((v >> 20) & 7u);
}

// -------- K0: convert fp32 -> fp8 e4m3, zero packed + scratch --------
__global__ __launch_bounds__(256)
void convert_kernel(const float* __restrict__ F, unsigned char* __restrict__ F8,
                    unsigned long long* __restrict__ packed,
                    unsigned long long* __restrict__ scratch)
{
    const int t = blockIdx.x * 256 + threadIdx.x;     // 524288 threads
    const float4 a = *reinterpret_cast<const float4*>(F + (size_t)t * 8);
    const float4 b = *reinterpret_cast<const float4*>(F + (size_t)t * 8 + 4);
    const unsigned lo = f2e4m3(a.x) | (f2e4m3(a.y) << 8) |
                        (f2e4m3(a.z) << 16) | (f2e4m3(a.w) << 24);
    const unsigned hi = f2e4m3(b.x) | (f2e4m3(b.y) << 8) |
                        (f2e4m3(b.z) << 16) | (f2e4m3(b.w) << 24);
    uint2 v; v.x = lo; v.y = hi;
    *reinterpret_cast<uint2*>(F8 + (size_t)t * 8) = v;
    if (t < NROWS) packed[t] = 0ull;
    #pragma unroll
    for (int q = 0; q < 4; ++q)                       // 2M u64 = 16 MB
        scratch[(size_t)t * 4 + q] = 0ull;
}

// -------- K1: symmetric fp8 MFMA + two-sided argmax --------
__global__ __launch_bounds__(256, 3)
void mfma_sym_fp8_kernel(const unsigned char* __restrict__ F8,
                         unsigned long long* __restrict__ packed,
                         unsigned long long* __restrict__ scratch)
{
    __shared__ __align__(16) unsigned char As[32768];   // [k16][row][16B]
    __shared__ __align__(16) unsigned char Bs[2 * 8192];// 2 x [k16][col][16B]

    const int tid  = threadIdx.x;
    const int w    = tid >> 6;
    const int l    = tid & 63;
    const int rs   = (int)blockIdx.x >> 3;      // row stripe 0..127
    const int ck   = (int)blockIdx.x & 7;       // chunk-of-stripe 0..7
    const int span = 128 - rs;
    const int t0   = rs + (span * ck) / 8;
    const int t1   = rs + (span * (ck + 1)) / 8;
    if (t0 >= t1) return;                       // block-uniform

    const int row0 = rs * BM;
    const int wrow = (w >> 1) * 64;
    const int wcol = (w & 1) * 64;
    const int lc   = l & 15;
    const int lr4  = l >> 4;

    // ---- stage A panel: 32 issues, cell q*64+l -> [k16=q>>1][row=(q&1)*64+l] ----
    #pragma unroll
    for (int m = 0; m < 8; ++m) {
        const int q   = 8 * w + m;              // 0..31
        const int k16 = q >> 1;
        const int row = (q & 1) * 64 + l;
        glds16(F8 + (size_t)(row0 + row) * DIM + k16 * 16, &As[q * 1024]);
    }

    // ---- stage first B slice (t0, slice 0) into slot 0 ----
    #pragma unroll
    for (int q2 = 0; q2 < 2; ++q2) {
        const int col = q2 * 64 + l;
        glds16(F8 + (size_t)(t0 * BM + col) * DIM + w * 16,
               &Bs[(2 * w + q2) * 1024]);
    }

    const long* __restrict__ Al = reinterpret_cast<const long*>(As);

    f32x4 acc[4][4];
    #pragma unroll
    for (int i = 0; i < 4; ++i)
        #pragma unroll
        for (int j = 0; j < 4; ++j)
            acc[i][j] = (f32x4){512.f, 512.f, 512.f, 512.f};   // monotonic bias

    unsigned best[4][4] = {};   // (biased bits & ~0x7FF) | (2047 - block-local col)

    const int k16r = (lr4 >> 1);
    const int odd  = lr4 & 1;

    for (int t = t0; t < t1; ++t) {
        const bool dt = (t == rs);              // diagonal tile
        #pragma unroll
        for (int ss = 0; ss < 4; ++ss) {        // K=64 slices
            __syncthreads();   // slice (t,ss) staged; prior reads of other slot done

            // prefetch next slice into the other slot
            const int nt  = (ss < 3) ? t : t + 1;
            const int nss = (ss < 3) ? ss + 1 : 0;
            if (nt < t1) {
                #pragma unroll
                for (int q2 = 0; q2 < 2; ++q2) {
                    const int col = q2 * 64 + l;
                    glds16(F8 + (size_t)(nt * BM + col) * DIM + nss * 64 + w * 16,
                           &Bs[((ss & 1) ^ 1) * 8192 + (2 * w + q2) * 1024]);
                }
            }

            const long* __restrict__ Bl =
                reinterpret_cast<const long*>(Bs) + (ss & 1) * 1024;

            #pragma unroll
            for (int h = 0; h < 2; ++h) {       // two K=32 MFMA steps
                const int kk = h * 2 + k16r;    // slice-local k16 0..3
                long afv[4], bfv[4];
                #pragma unroll
                for (int i = 0; i < 4; ++i) {
                    const int r = wrow + i * 16 + lc;
                    afv[i] = Al[(ss * 4 + kk) * 256 + r * 2 + odd];
                }
                #pragma unroll
                for (int j = 0; j < 4; ++j) {
                    const int c = wcol + j * 16 + lc;
                    bfv[j] = Bl[kk * 256 + c * 2 + odd];
                }
                #pragma unroll
                for (int j = 0; j < 4; ++j)
                    #pragma unroll
                    for (int i = 0; i < 4; ++i)
                        acc[i][j] = __builtin_amdgcn_mfma_f32_16x16x32_fp8_fp8(
                            afv[i], bfv[j], acc[i][j], 0, 0, 0);
            }
        }

        // ---- B-side fold: per-column max over the tile's 128 rows ----
        #pragma unroll
        for (int j = 0; j < 4; ++j) {
            unsigned kb = 0u;
            #pragma unroll
            for (int i = 0; i < 4; ++i)
                #pragma unroll
                for (int g = 0; g < 4; ++g) {
                    const int r_loc = wrow + i * 16 + lr4 * 4 + g;
                    unsigned key = (__float_as_uint(acc[i][j][g]) & 0xFFFFF800u)
                                   | (unsigned)(127 - r_loc);
                    if (dt && (wcol + j * 16 + lc == r_loc)) key = 0u;
                    kb = umax2(kb, key);
                }
            kb = umax2(kb, (unsigned)__shfl_xor((int)kb, 16));
            kb = umax2(kb, (unsigned)__shfl_xor((int)kb, 32));
            if (lr4 == 0) {    // 64-row half max -> one atomic per col per half
                const unsigned grow = (unsigned)row0 + (127u - (kb & 0x7FFu));
                const unsigned long long pk =
                    ((unsigned long long)(kb & 0xFFFFF800u) << 32) |
                    (0xFFFFFFFFu - grow);
                atomicMax(&scratch[((size_t)t * 128 + rs) * 128
                                   + wcol + j * 16 + lc], pk);
            }
        }

        // ---- A-side fold into running per-row argmax ----
        const int tl = t - t0;                   // block-local tile (<=15)
        unsigned cb[4];
        #pragma unroll
        for (int j = 0; j < 4; ++j)
            cb[j] = 2047u - (unsigned)(tl * 128 + wcol + j * 16 + lc);

        if (dt) {
            #pragma unroll
            for (int i = 0; i < 4; ++i)
                #pragma unroll
                for (int g = 0; g < 4; ++g) {
                    const int r_loc = wrow + i * 16 + lr4 * 4 + g;
                    unsigned bk = best[i][g];
                    #pragma unroll
                    for (int j = 0; j < 4; ++j) {
                        unsigned key = (__float_as_uint(acc[i][j][g])
                                        & 0xFFFFF800u) | cb[j];
                        if (wcol + j * 16 + lc == r_loc) key = 0u;
                        bk = umax2(bk, key);
                        acc[i][j][g] = 512.f;
                    }
                    best[i][g] = bk;
                }
        } else {
            #pragma unroll
            for (int i = 0; i < 4; ++i)
                #pragma unroll
                for (int g = 0; g < 4; ++g) {
                    const unsigned k0 = (__float_as_uint(acc[i][0][g]) & 0xFFFFF800u) | cb[0];
                    const unsigned k1 = (__float_as_uint(acc[i][1][g]) & 0xFFFFF800u) | cb[1];
                    const unsigned k2 = (__float_as_uint(acc[i][2][g]) & 0xFFFFF800u) | cb[2];
                    const unsigned k3 = (__float_as_uint(acc[i][3][g]) & 0xFFFFF800u) | cb[3];
                    best[i][g] = umax2(best[i][g],
                                       umax2(umax2(k0, k1), umax2(k2, k3)));
                    acc[i][0][g] = 512.f; acc[i][1][g] = 512.f;
                    acc[i][2][g] = 512.f; acc[i][3][g] = 512.f;
                }
        }
    }

    // ---- A-side: reduce over 16-lane col group, one u64 atomic per row ----
    #pragma unroll
    for (int i = 0; i < 4; ++i)
        #pragma unroll
        for (int g = 0; g < 4; ++g) {
            unsigned key = best[i][g];
            #pragma unroll
            for (int m = 8; m >= 1; m >>= 1)
                key = umax2(key, (unsigned)__shfl_xor((int)key, m));
            if (lc == 0) {
                const int r = row0 + wrow + i * 16 + lr4 * 4 + g;
                const unsigned c = (unsigned)(t0 * BM) + (2047u - (key & 0x7FFu));
                const unsigned long long pk =
                    ((unsigned long long)(key & 0xFFFFF800u) << 32) |
                    (0xFFFFFFFFu - c);
                atomicMax(&packed[r], pk);
            }
        }
}

// ------- K2: merge two-sided candidates + exact fp32 distances + log -------
__global__ __launch_bounds__(256)
void dist_loss_kernel(const float* __restrict__ F,
                      const unsigned long long* __restrict__ packed,
                      const unsigned long long* __restrict__ scratch,
                      double* __restrict__ partials)
{
    const int tid  = threadIdx.x;
    const int lane = tid & 63;
    const int w    = tid >> 6;
    const int gw   = blockIdx.x * 4 + w;       // 1024 waves
    double local = 0.0;
    for (int r = gw; r < NROWS; r += 1024) {
        const int tR = r >> 7;
        const int cl = r & 127;
        unsigned long long best = packed[r];
        const unsigned long long* base = scratch + (size_t)tR * 16384 + cl;
        if (lane <= tR) {
            unsigned long long v = base[(size_t)lane * 128];
            if (lane + 64 <= tR) {
                const unsigned long long v2 = base[(size_t)(lane + 64) * 128];
                if (v2 > v) v = v2;
            }
            if (v > best) best = v;
        }
        #pragma unroll
        for (int m = 32; m >= 1; m >>= 1) {
            const unsigned long long o = __shfl_xor(best, m);
            if (o > best) best = o;
        }
        const int idx = (int)(0xFFFFFFFFu - (unsigned)(best & 0xFFFFFFFFull));

        const float4 a = *reinterpret_cast<const float4*>(
            F + (size_t)r * DIM + (lane << 2));
        const float4 b = *reinterpret_cast<const float4*>(
            F + (size_t)idx * DIM + (lane << 2));
        const float dx = a.x - b.x + EPSF;
        const float dy = a.y - b.y + EPSF;
        const float dz = a.z - b.z + EPSF;
        const float dw = a.w - b.w + EPSF;
        float ss = dx * dx + dy * dy + dz * dz + dw * dw;
        #pragma unroll
        for (int m = 32; m >= 1; m >>= 1) ss += __shfl_xor(ss, m);
        if (lane == 0)
            local += 0.5 * log((double)ss) + log((double)NROWS);
    }
    __shared__ double sm[4];
    if (lane == 0) sm[w] = local;
    __syncthreads();
    if (tid == 0) partials[blockIdx.x] = sm[0] + sm[1] + sm[2] + sm[3];
}

__global__ __launch_bounds__(256)
void finalize_kernel(const double* __restrict__ partials, float* __restrict__ out)
{
    const int tid = threadIdx.x;
    double v = partials[tid];
    #pragma unroll
    for (int m = 32; m >= 1; m >>= 1) v += __shfl_xor(v, m);
    __shared__ double sm[4];
    if ((tid & 63) == 0) sm[tid >> 6] = v;
    __syncthreads();
    if (tid == 0) out[0] = (float)(-(sm[0] + sm[1] + sm[2] + sm[3]) / (double)NROWS);
}

extern "C" void kernel_launch(void* const* d_in, const int* in_sizes, int n_in,
                              void* d_out, int out_size, void* d_ws, size_t ws_size,
                              hipStream_t stream)
{
    const float* F   = (const float*)d_in[0];
    float*       out = (float*)d_out;

    char* ws = (char*)d_ws;
    unsigned char*      F8       = (unsigned char*)ws;                   // 4 MB
    unsigned long long* packed   = (unsigned long long*)(ws + 4194304);  // 128 KB
    unsigned long long* scratch  = (unsigned long long*)(ws + 4325376);  // 16 MB
    double*             partials = (double*)(ws + 21102592);             // 2 KB

    convert_kernel<<<2048, 256, 0, stream>>>(F, F8, packed, scratch);
    mfma_sym_fp8_kernel<<<(NROWS / BM) * 8, 256, 0, stream>>>(F8, packed, scratch);
    dist_loss_kernel<<<256, 256, 0, stream>>>(F, packed, scratch, partials);
    finalize_kernel<<<1, 256, 0, stream>>>(partials, out);
}